// Round 7
// baseline (286.818 us; speedup 1.0000x reference)
//
#include <hip/hip_runtime.h>
#include <hip/hip_bf16.h>
#include <stdint.h>

typedef __attribute__((ext_vector_type(8))) short short8;
typedef __attribute__((ext_vector_type(4))) float floatx4;
typedef __attribute__((ext_vector_type(8))) int int8v;
typedef __attribute__((ext_vector_type(4))) int int4v;

__device__ __forceinline__ ushort f2b(float f) {
    union { float f; uint32_t u; } v; v.f = f;
    uint32_t r = (v.u + 0x7fffu + ((v.u >> 16) & 1u)) >> 16;
    return (ushort)r;
}
__device__ __forceinline__ float b2f(ushort b) {
    union { uint32_t u; float f; } v; v.u = ((uint32_t)b) << 16;
    return v.f;
}
__device__ __forceinline__ uint8_t f2fp8(float f) {
    return (uint8_t)(__builtin_amdgcn_cvt_pk_fp8_f32(f, f, 0, false) & 0xff);
}

__device__ __forceinline__ void gl_lds16(const void* g, void* l) {
    __builtin_amdgcn_global_load_lds(
        (const __attribute__((address_space(1))) void*)g,
        (__attribute__((address_space(3))) void*)l, 16, 0, 0);
}

// ================= prep mega-kernel: all elementwise/transpose prep in ONE launch ====
__global__ __launch_bounds__(256) void prep_all(
    const float* __restrict__ x, const float* __restrict__ Wq,
    const float* __restrict__ Wk, const float* __restrict__ fcw,
    const float* __restrict__ concepts,
    uint8_t* __restrict__ x_f8, ushort* __restrict__ Wq_bf,
    ushort* __restrict__ Wk_bf, ushort* __restrict__ fcw_bf,
    ushort* __restrict__ c_bf, uint8_t* __restrict__ cT_f8,
    uint8_t* __restrict__ W3T_f8)
{
    __shared__ float smem_f[8];
    __shared__ float partial[32][8];
    __shared__ float invn[32];
    __shared__ uint8_t tile8[32 * 1044];

    int b = blockIdx.x;
    const int tid = threadIdx.x;

    if (b < 16384) {                       // x -> fp8
        int i = b * 256 + tid;
        float4 v = ((const float4*)x)[i];
        int p = __builtin_amdgcn_cvt_pk_fp8_f32(v.x, v.y, 0, false);
        p = __builtin_amdgcn_cvt_pk_fp8_f32(v.z, v.w, p, true);
        ((uint32_t*)x_f8)[i] = p;
        return;
    }
    b -= 16384;
    if (b < 1024) {                        // Wq -> bf16
        int i = b * 256 + tid;
        float4 v = ((const float4*)Wq)[i];
        ushort4 o; o.x = f2b(v.x); o.y = f2b(v.y); o.z = f2b(v.z); o.w = f2b(v.w);
        ((ushort4*)Wq_bf)[i] = o;
        return;
    }
    b -= 1024;
    if (b < 1024) {                        // Wk -> bf16
        int i = b * 256 + tid;
        float4 v = ((const float4*)Wk)[i];
        ushort4 o; o.x = f2b(v.x); o.y = f2b(v.y); o.z = f2b(v.z); o.w = f2b(v.w);
        ((ushort4*)Wk_bf)[i] = o;
        return;
    }
    b -= 1024;
    if (b < 1000) {                        // fc_w -> bf16
        int i = b * 256 + tid;
        float4 v = ((const float4*)fcw)[i];
        ushort4 o; o.x = f2b(v.x); o.y = f2b(v.y); o.z = f2b(v.z); o.w = f2b(v.w);
        ((ushort4*)fcw_bf)[i] = o;
        return;
    }
    b -= 1000;
    if (b < 512) {                         // concept row L2-normalize -> bf16
        const float* xr = concepts + (size_t)b * 1024;
        float vv[4]; float s = 0.0f;
        #pragma unroll
        for (int j = 0; j < 4; j++) { vv[j] = xr[tid + 256 * j]; s += vv[j] * vv[j]; }
        #pragma unroll
        for (int off = 32; off; off >>= 1) s += __shfl_down(s, off, 64);
        if ((tid & 63) == 0) smem_f[tid >> 6] = s;
        __syncthreads();
        float inv = rsqrtf(smem_f[0] + smem_f[1] + smem_f[2] + smem_f[3]);
        ushort* o = c_bf + (size_t)b * 1024;
        #pragma unroll
        for (int j = 0; j < 4; j++) o[tid + 256 * j] = f2b(vv[j] * inv);
        return;
    }
    b -= 512;
    if (b < 16) {                          // cT_f8: rows r0..r0+31, all 1024 cols
        const int r0 = b * 32;
        {
            int row = tid >> 3, sub = tid & 7;
            const float* rp = concepts + (size_t)(r0 + row) * 1024 + sub * 128;
            float s = 0.0f;
            #pragma unroll
            for (int j = 0; j < 32; j++) {
                float4 v = ((const float4*)rp)[j];
                s += v.x * v.x + v.y * v.y + v.z * v.z + v.w * v.w;
            }
            partial[row][sub] = s;
        }
        __syncthreads();
        if (tid < 32) {
            float t = 0.0f;
            #pragma unroll
            for (int j = 0; j < 8; j++) t += partial[tid][j];
            invn[tid] = rsqrtf(t);
        }
        __syncthreads();
        for (int idx = tid; idx < 32 * 256; idx += 256) {
            int row = idx >> 8, d4 = idx & 255;
            float4 v = ((const float4*)(concepts + (size_t)(r0 + row) * 1024))[d4];
            float sc = invn[row] * 16.0f;
            int p = __builtin_amdgcn_cvt_pk_fp8_f32(v.x * sc, v.y * sc, 0, false);
            p = __builtin_amdgcn_cvt_pk_fp8_f32(v.z * sc, v.w * sc, p, true);
            *(uint32_t*)&tile8[row * 1044 + d4 * 4] = p;
        }
        __syncthreads();
        for (int idx = tid; idx < 32 * 1024; idx += 256) {
            int d = idx >> 5, row = idx & 31;
            cT_f8[(size_t)d * 512 + r0 + row] = tile8[row * 1044 + d];
        }
        return;
    }
    {                                      // zero W3T rows 1000..1023
        uint32_t* p = (uint32_t*)(W3T_f8 + 1000 * 512);
        #pragma unroll
        for (int k = 0; k < 12; k++) p[tid + 256 * k] = 0u;
    }
}

// =============== MX-fp8 MFMA GEMM: C = scale*(A @ B^T) [+bias][*rsqrt(rn)] ==========
template<typename OutT, bool NGUARD, bool SUMSQ, bool ROWSCALE, bool STORE>
__global__ __launch_bounds__(256, 3) void gemm_f8(
    const uint8_t* __restrict__ A, const uint8_t* __restrict__ B,
    const float* __restrict__ bias, float* __restrict__ rn, OutT* __restrict__ C,
    int M, int N, int K, int Nld, float scale)
{
    __shared__ alignas(16) uint8_t As[128 * 128];
    __shared__ alignas(16) uint8_t Bs[128 * 128];
    const int id = threadIdx.x;
    const int wave = id >> 6, lane = id & 63;

    int bxi = blockIdx.x, byi = blockIdx.y;
    if ((gridDim.y & 7) == 0) {
        int i = byi * gridDim.x + bxi;
        int xcd = i & 7;
        int j = i >> 3;
        bxi = j % gridDim.x;
        byi = xcd + 8 * (j / gridDim.x);
    }
    const int row0 = byi * 128, col0 = bxi * 128;
    const int wm = (wave >> 1) * 64, wn = (wave & 1) * 64;

    const int fr = id >> 3;
    const int fss = (id & 7) ^ (fr & 7);
    const uint8_t* Agp[4];
    const uint8_t* Bgp[4];
    #pragma unroll
    for (int t = 0; t < 4; t++) {
        int ar = row0 + fr + 32 * t;
        int br = col0 + fr + 32 * t;
        if (NGUARD) br = min(br, N - 1);
        Agp[t] = A + (size_t)ar * K + fss * 16;
        Bgp[t] = B + (size_t)br * K + fss * 16;
    }

    floatx4 acc[4][4] = {};
    const int mrow = lane & 15;
    const int g2 = (lane >> 4) * 2;

    for (int k0 = 0; k0 < K; k0 += 128) {
        #pragma unroll
        for (int t = 0; t < 4; t++) {
            gl_lds16(Agp[t] + k0, &As[id * 16 + 4096 * t]);
            gl_lds16(Bgp[t] + k0, &Bs[id * 16 + 4096 * t]);
        }
        __syncthreads();
        int8v a[4], b[4];
        #pragma unroll
        for (int i = 0; i < 4; i++) {
            int r = wm + i * 16 + mrow, rs = r & 7;
            int4v lo = *(const int4v*)&As[r * 128 + ((g2    ) ^ rs) * 16];
            int4v hi = *(const int4v*)&As[r * 128 + ((g2 + 1) ^ rs) * 16];
            a[i] = __builtin_shufflevector(lo, hi, 0, 1, 2, 3, 4, 5, 6, 7);
        }
        #pragma unroll
        for (int j = 0; j < 4; j++) {
            int r = wn + j * 16 + mrow, rs = r & 7;
            int4v lo = *(const int4v*)&Bs[r * 128 + ((g2    ) ^ rs) * 16];
            int4v hi = *(const int4v*)&Bs[r * 128 + ((g2 + 1) ^ rs) * 16];
            b[j] = __builtin_shufflevector(lo, hi, 0, 1, 2, 3, 4, 5, 6, 7);
        }
        #pragma unroll
        for (int i = 0; i < 4; i++)
            #pragma unroll
            for (int j = 0; j < 4; j++)
                acc[i][j] = __builtin_amdgcn_mfma_scale_f32_16x16x128_f8f6f4(
                    a[i], b[j], acc[i][j], 0, 0, 0, 0x7f7f7f7f, 0, 0x7f7f7f7f);
        __syncthreads();
    }

    const int ccol0 = col0 + wn + (lane & 15);
    const int crow0 = row0 + wm + (lane >> 4) * 4;
    float bv[4];
    #pragma unroll
    for (int j = 0; j < 4; j++) {
        int col = ccol0 + j * 16;
        bv[j] = (bias && (!NGUARD || col < N)) ? bias[col] : 0.0f;
    }
    #pragma unroll
    for (int i = 0; i < 4; i++) {
        #pragma unroll
        for (int r = 0; r < 4; r++) {
            const int row = crow0 + i * 16 + r;
            float inv = 1.0f;
            if constexpr (ROWSCALE) inv = rsqrtf(rn[row]);
            float ss = 0.0f;
            #pragma unroll
            for (int j = 0; j < 4; j++) {
                int col = ccol0 + j * 16;
                float v = acc[i][j][r] * scale * inv + bv[j];
                if constexpr (SUMSQ) ss += v * v;
                if constexpr (STORE) {
                    if (!NGUARD || col < N) {
                        if constexpr (sizeof(OutT) == 1)      C[(size_t)row * Nld + col] = (OutT)f2fp8(v);
                        else if constexpr (sizeof(OutT) == 2) C[(size_t)row * Nld + col] = (OutT)f2b(v);
                        else                                   C[(size_t)row * Nld + col] = v;
                    }
                }
            }
            if constexpr (SUMSQ) {
                #pragma unroll
                for (int m = 1; m < 16; m <<= 1) ss += __shfl_xor(ss, m, 64);
                if ((lane & 15) == 0) atomicAdd(&rn[row], ss);
            }
        }
    }
}

// =============== shared 64x64 bf16 GEMM body ==========
__device__ __forceinline__ void gemm64_body(
    uint8_t* As, uint8_t* Bs,
    const ushort* __restrict__ A, const ushort* __restrict__ B, void* Cout, int outmode,
    int M, int N, int K, int Nld, float scale, int bx, int by, bool mguard)
{
    const int id = threadIdx.x;
    const int wave = id >> 6, lane = id & 63;
    const int row0 = by * 64, col0 = bx * 64;
    const int wm = (wave >> 1) * 32, wn = (wave & 1) * 32;

    const int fr = id >> 4;
    const int sch = (id & 15) ^ (fr & 7);
    const uint8_t* Ab = (const uint8_t*)A;
    const uint8_t* Bb = (const uint8_t*)B;
    const uint8_t* Agp[4];
    const uint8_t* Bgp[4];
    #pragma unroll
    for (int t = 0; t < 4; t++) {
        int ar = row0 + fr + 16 * t;
        if (mguard) ar = min(ar, M - 1);
        int br = col0 + fr + 16 * t;
        Agp[t] = Ab + (size_t)ar * (K * 2) + sch * 16;
        Bgp[t] = Bb + (size_t)br * (K * 2) + sch * 16;
    }

    floatx4 acc[2][2] = {};
    const int mrow = lane & 15, g = lane >> 4;

    for (int k0 = 0; k0 < K; k0 += 128) {
        #pragma unroll
        for (int t = 0; t < 4; t++) {
            gl_lds16(Agp[t] + (size_t)k0 * 2, &As[id * 16 + 4096 * t]);
            gl_lds16(Bgp[t] + (size_t)k0 * 2, &Bs[id * 16 + 4096 * t]);
        }
        __syncthreads();
        #pragma unroll
        for (int ks = 0; ks < 4; ks++) {
            short8 a[2], b[2];
            #pragma unroll
            for (int i = 0; i < 2; i++) {
                int r = wm + i * 16 + mrow;
                a[i] = *(const short8*)&As[r * 256 + ((ks * 4 + g) ^ (r & 7)) * 16];
            }
            #pragma unroll
            for (int j = 0; j < 2; j++) {
                int r = wn + j * 16 + mrow;
                b[j] = *(const short8*)&Bs[r * 256 + ((ks * 4 + g) ^ (r & 7)) * 16];
            }
            #pragma unroll
            for (int i = 0; i < 2; i++)
                #pragma unroll
                for (int j = 0; j < 2; j++)
                    acc[i][j] = __builtin_amdgcn_mfma_f32_16x16x32_bf16(a[i], b[j], acc[i][j], 0, 0, 0);
        }
        __syncthreads();
    }

    const int ccol0 = col0 + wn + (lane & 15);
    const int crow0 = row0 + wm + (lane >> 4) * 4;
    #pragma unroll
    for (int i = 0; i < 2; i++) {
        #pragma unroll
        for (int r = 0; r < 4; r++) {
            const int row = crow0 + i * 16 + r;
            if (mguard && row >= M) continue;
            #pragma unroll
            for (int j = 0; j < 2; j++) {
                int col = ccol0 + j * 16;
                float v = acc[i][j][r] * scale;
                if (outmode == 0)      ((float*)Cout)[(size_t)row * Nld + col] = v;
                else if (outmode == 1) ((uint8_t*)Cout)[(size_t)row * Nld + col] = f2fp8(v);
                else                   ((ushort*)Cout)[(size_t)row * Nld + col] = f2b(v);
            }
        }
    }
}

// P2 = Wq @ Wk^T   [1024,1024] bf16
__global__ __launch_bounds__(256) void gemm_p2(const ushort* __restrict__ Wq_bf,
                                               const ushort* __restrict__ Wk_bf,
                                               ushort* __restrict__ P2) {
    __shared__ alignas(16) uint8_t As[64 * 256];
    __shared__ alignas(16) uint8_t Bs[64 * 256];
    gemm64_body(As, Bs, Wq_bf, Wk_bf, P2, 2, 1024, 1024, 1024, 1024, 1.0f,
                blockIdx.x, blockIdx.y, false);
}

// batched: sim = c@c^T (f32) | W3T = fcw@c^T (fp8*16) | W2T = c@P2^T (fp8*16)
__global__ __launch_bounds__(256) void gemm_batch3(
    const ushort* __restrict__ c_bf, const ushort* __restrict__ fcw_bf,
    const ushort* __restrict__ P2,
    float* __restrict__ sim, uint8_t* __restrict__ W3T, uint8_t* __restrict__ W2T)
{
    __shared__ alignas(16) uint8_t As[64 * 256];
    __shared__ alignas(16) uint8_t Bs[64 * 256];
    int b = blockIdx.x;
    if (b < 64) {
        gemm64_body(As, Bs, c_bf, c_bf, sim, 0, 512, 512, 1024, 512, 1.0f, b & 7, b >> 3, false);
    } else if (b < 192) {
        b -= 64;
        gemm64_body(As, Bs, fcw_bf, c_bf, W3T, 1, 1000, 512, 1024, 512, 16.0f, b & 7, b >> 3, true);
    } else {
        b -= 192;
        gemm64_body(As, Bs, c_bf, P2, W2T, 1, 512, 1024, 1024, 1024, 16.0f, b & 15, b >> 4, false);
    }
}

// ===== fused scores + sparsemax + rn: 32 rows/block, 512 blocks, 2 blocks/CU =====
// Phase 1: scores = (x_f8 @ W2T^T)/512; wave owns 32 rows x 128 cols (acc[2][8])
// Phase 2: f32 scores exchanged through LDS (chunk-XOR swizzle); each wave owns
//          8 full rows (8-lane groups) -> wave-local Newton sparsemax [R4-proven math]
// Phase 3: attn f32 + fp8 -> global (float4/int4 coalesced); fp8 -> LDS at8 (swizzled)
// Phase 4: rn = |attn @ c|^2; A-frags in regs, B-frags read direct from L2-resident cT
//          (byte-identical offsets to the staged variant), no barriers; block-local reduce.
__global__ __launch_bounds__(256, 2) void scores_sm_rn(
    const uint8_t* __restrict__ X, const uint8_t* __restrict__ W2T,
    const uint8_t* __restrict__ cT,
    float* __restrict__ attn, uint8_t* __restrict__ A8, float* __restrict__ rn)
{
    // LDS 70144 B: As [0,4K) | Bs [4K,68.5K)  -> phase 1
    //              sc (f32 [32][512]) = Bs region | at8 [0,16K) (after sc reads done)
    //              rnred [68.5K, +512)
    __shared__ alignas(16) uint8_t lds[70144];
    uint8_t* As  = lds;
    uint8_t* Bs  = lds + 4096;
    float*   sc  = (float*)(lds + 4096);
    uint8_t* at8 = lds;
    float* rnred = (float*)(lds + 69632);

    const int id = threadIdx.x;
    const int wave = id >> 6, lane = id & 63;
    const int row0 = blockIdx.x * 32;
    const int mrow = lane & 15;
    const int g = lane >> 4;
    const int g2 = g * 2;

    // ---------------- phase 1: scores GEMM (32 x 512, K=1024) ----------------
    {
        const int srow = id >> 3;                   // 0..31
        const int fss = (id & 7) ^ (srow & 7);
        const uint8_t* Ag = X + (size_t)(row0 + srow) * 1024 + fss * 16;
        const uint8_t* Bg = W2T + (size_t)srow * 1024 + fss * 16;

        floatx4 acc[2][8] = {};
        for (int k0 = 0; k0 < 1024; k0 += 128) {
            gl_lds16(Ag + k0, &As[id * 16]);
            #pragma unroll
            for (int t = 0; t < 16; t++)
                gl_lds16(Bg + k0 + (size_t)t * 32 * 1024, &Bs[(id + 256 * t) * 16]);
            __syncthreads();
            int8v a[2], b[8];
            #pragma unroll
            for (int mt = 0; mt < 2; mt++) {
                int r = mt * 16 + mrow, rs = r & 7;
                int4v lo = *(const int4v*)&As[r * 128 + ((g2    ) ^ rs) * 16];
                int4v hi = *(const int4v*)&As[r * 128 + ((g2 + 1) ^ rs) * 16];
                a[mt] = __builtin_shufflevector(lo, hi, 0, 1, 2, 3, 4, 5, 6, 7);
            }
            #pragma unroll
            for (int j = 0; j < 8; j++) {
                int r = wave * 128 + j * 16 + mrow, rs = r & 7;
                int4v lo = *(const int4v*)&Bs[r * 128 + ((g2    ) ^ rs) * 16];
                int4v hi = *(const int4v*)&Bs[r * 128 + ((g2 + 1) ^ rs) * 16];
                b[j] = __builtin_shufflevector(lo, hi, 0, 1, 2, 3, 4, 5, 6, 7);
            }
            #pragma unroll
            for (int mt = 0; mt < 2; mt++)
                #pragma unroll
                for (int j = 0; j < 8; j++)
                    acc[mt][j] = __builtin_amdgcn_mfma_scale_f32_16x16x128_f8f6f4(
                        a[mt], b[j], acc[mt][j], 0, 0, 0, 0x7f7f7f7f, 0, 0x7f7f7f7f);
            __syncthreads();
        }

        // scores (scaled) -> sc with 16B-chunk XOR swizzle (word-exact round trip)
        #pragma unroll
        for (int mt = 0; mt < 2; mt++)
            #pragma unroll
            for (int j = 0; j < 8; j++) {
                int col = wave * 128 + j * 16 + mrow;
                int c = col >> 2, w2 = col & 3;
                #pragma unroll
                for (int r = 0; r < 4; r++) {
                    int row = mt * 16 + g * 4 + r;
                    sc[row * 512 + ((c ^ (row & 7)) << 2) + w2] = acc[mt][j][r] * (1.0f / 512.0f);
                }
            }
    }
    __syncthreads();

    // ---------------- phase 2: redistribute + wave-local Newton ----------------
    const int orow = wave * 8 + (lane >> 3);        // this lane's owned row (0..31)
    const int cc = lane & 7;                        // col block: cols cc*64 .. cc*64+63
    const int ors = orow & 7;
    float4 v4[16];
    #pragma unroll
    for (int k4 = 0; k4 < 16; k4++) {
        int phys = (cc * 16 + k4) ^ ors;
        v4[k4] = *(const float4*)&sc[orow * 512 + phys * 4];
    }
    __syncthreads();                                // sc reads done -> at8 region free

    float mx = v4[0].x;
    #pragma unroll
    for (int k4 = 0; k4 < 16; k4++)
        mx = fmaxf(mx, fmaxf(fmaxf(v4[k4].x, v4[k4].y), fmaxf(v4[k4].z, v4[k4].w)));
    #pragma unroll
    for (int off = 1; off < 8; off <<= 1) mx = fmaxf(mx, __shfl_xor(mx, off, 64));
    // Newton on f(tau)=sum(max(v-tau,0))-1: monotone from below, k>=1 always.
    float tau = mx - 1.0f;
    for (int it = 0; it < 12; it++) {
        float s = 0.0f, k = 0.0f;
        #pragma unroll
        for (int k4 = 0; k4 < 16; k4++) {
            float d;
            d = v4[k4].x - tau; if (d > 0.0f) { s += d; k += 1.0f; }
            d = v4[k4].y - tau; if (d > 0.0f) { s += d; k += 1.0f; }
            d = v4[k4].z - tau; if (d > 0.0f) { s += d; k += 1.0f; }
            d = v4[k4].w - tau; if (d > 0.0f) { s += d; k += 1.0f; }
        }
        #pragma unroll
        for (int off = 1; off < 8; off <<= 1) {
            s += __shfl_xor(s, off, 64);
            k += __shfl_xor(k, off, 64);
        }
        tau += (s - 1.0f) / k;
    }

    // ---------------- phase 3: outputs (attn f32, fp8 global, fp8 LDS) ----------------
    {
        float* ag = attn + (size_t)(row0 + orow) * 512 + cc * 64;
        uint8_t* a8g = A8 + (size_t)(row0 + orow) * 512 + cc * 64;
        #pragma unroll
        for (int q = 0; q < 4; q++) {
            int4v pk;
            #pragma unroll
            for (int h = 0; h < 4; h++) {
                float4 v = v4[q * 4 + h];
                float4 o;
                o.x = fmaxf(v.x - tau, 0.0f);
                o.y = fmaxf(v.y - tau, 0.0f);
                o.z = fmaxf(v.z - tau, 0.0f);
                o.w = fmaxf(v.w - tau, 0.0f);
                ((float4*)ag)[q * 4 + h] = o;
                int p = __builtin_amdgcn_cvt_pk_fp8_f32(o.x * 32.0f, o.y * 32.0f, 0, false);
                p = __builtin_amdgcn_cvt_pk_fp8_f32(o.z * 32.0f, o.w * 32.0f, p, true);
                pk[h] = p;
            }
            *(int4v*)(a8g + q * 16) = pk;
            *(int4v*)&at8[orow * 512 + (((cc * 4 + q) ^ ors) << 4)] = pk;
        }
    }
    __syncthreads();

    // ---------------- cached A-fragments (attn 32 rows, K=512) ----------------
    int8v a_all[2][4];
    #pragma unroll
    for (int mt = 0; mt < 2; mt++) {
        const int ar = mt * 16 + mrow;
        const int rs = ar & 7;
        #pragma unroll
        for (int ks = 0; ks < 4; ks++) {
            int4v lo = *(const int4v*)&at8[ar * 512 + (((ks * 8 + g2    ) ^ rs) << 4)];
            int4v hi = *(const int4v*)&at8[ar * 512 + (((ks * 8 + g2 + 1) ^ rs) << 4)];
            a_all[mt][ks] = __builtin_shufflevector(lo, hi, 0, 1, 2, 3, 4, 5, 6, 7);
        }
    }

    // ---------------- phase 4: rn, B-frags direct from L2-resident cT ----------------
    float ss[8] = {};
    #pragma unroll 2
    for (int seg = 0; seg < 16; seg++) {
        const int col = seg * 64 + wave * 16 + mrow;         // cT row 0..1023
        const uint8_t* bp = cT + (size_t)col * 512 + g * 32;
        floatx4 acc_t[2] = {};
        #pragma unroll
        for (int ks = 0; ks < 4; ks++) {
            int4v lo = *(const int4v*)(bp + ks * 128);
            int4v hi = *(const int4v*)(bp + ks * 128 + 16);
            int8v b = __builtin_shufflevector(lo, hi, 0, 1, 2, 3, 4, 5, 6, 7);
            acc_t[0] = __builtin_amdgcn_mfma_scale_f32_16x16x128_f8f6f4(
                a_all[0][ks], b, acc_t[0], 0, 0, 0, 0x7f7f7f7f, 0, 0x7f7f7f7f);
            acc_t[1] = __builtin_amdgcn_mfma_scale_f32_16x16x128_f8f6f4(
                a_all[1][ks], b, acc_t[1], 0, 0, 0, 0x7f7f7f7f, 0, 0x7f7f7f7f);
        }
        #pragma unroll
        for (int mt = 0; mt < 2; mt++)
            #pragma unroll
            for (int r = 0; r < 4; r++) {
                float v = acc_t[mt][r] * (1.0f / 512.0f);
                ss[mt * 4 + r] += v * v;
            }
    }

    // reduce over the 16 n-lanes, then cross-wave, then direct write
    #pragma unroll
    for (int i = 0; i < 8; i++) {
        #pragma unroll
        for (int off = 1; off < 16; off <<= 1) ss[i] += __shfl_xor(ss[i], off, 64);
    }
    if (mrow == 0) {
        #pragma unroll
        for (int mt = 0; mt < 2; mt++)
            #pragma unroll
            for (int r = 0; r < 4; r++)
                rnred[wave * 32 + mt * 16 + g * 4 + r] = ss[mt * 4 + r];
    }
    __syncthreads();
    if (id < 32)
        rn[row0 + id] = rnred[id] + rnred[32 + id] + rnred[64 + id] + rnred[96 + id];
}

extern "C" void kernel_launch(void* const* d_in, const int* in_sizes, int n_in,
                              void* d_out, int out_size, void* d_ws, size_t ws_size,
                              hipStream_t stream) {
    const float* x        = (const float*)d_in[0];   // [16384,1024]
    const float* concepts = (const float*)d_in[1];   // [512,1024]
    const float* Wq       = (const float*)d_in[2];   // [1024,1024]
    const float* Wk       = (const float*)d_in[3];   // [1024,1024]
    const float* fc_w     = (const float*)d_in[4];   // [1000,1024]
    const float* fc_b     = (const float*)d_in[5];   // [1000]

    const int B = 16384, D = 1024, C = 512, N = 1000;

    float* out  = (float*)d_out;                       // [B,N]
    float* attn = out + (size_t)B * N;                 // [B,C]
    float* sim  = attn + (size_t)B * C;                // [C,C]

    // ---- ws layout (~34.6 MiB) ----
    uint8_t* w = (uint8_t*)d_ws;
    uint8_t* x_f8    = w;                                        // [B,D]     16 MiB
    uint8_t* attn_f8 = w + (16ull << 20);                        // [B,C]      8 MiB
    ushort*  Wq_bf   = (ushort*)(w + (24ull << 20));             // [D,D]      2 MiB
    ushort*  Wk_bf   = (ushort*)(w + (26ull << 20));             // [D,D]      2 MiB
    ushort*  fcw_bf  = (ushort*)(w + (28ull << 20));             // [N,D]      2 MiB
    ushort*  c_bf    = (ushort*)(w + (30ull << 20));             // [C,D]      1 MiB
    ushort*  P2_bf   = (ushort*)(w + (31ull << 20));             // [D,D]      2 MiB
    uint8_t* cT_f8   = w + (33ull << 20);                        // [D,C]    0.5 MiB
    uint8_t* W2T_f8  = w + (33ull << 20) + (512ull << 10);       // [C,D]    0.5 MiB
    uint8_t* W3T_f8  = w + (34ull << 20);                        // [1024,C] 0.5 MiB (tail rows zeroed)
    float*   rn      = (float*)(w + (34ull << 20) + (512ull << 10)); // [B] 64 KiB

    // Reassociation: scores = x @ W2T^T where W2T = c @ (Wq Wk^T)^T  (P2 = Wq @ Wk^T)
    //                out    = (attn @ W3T^T) * rsqrt(|attn@c|^2) + b (W3T = fcw @ c^T)
    // scales: x*1, W2T*16 -> scores scale (1/32)/16 = 1/512 (f32)
    //         attn*32, cT*16 -> rn = |acc/512|^2 (in-kernel, direct write)
    //         attn*32, W3T*16 -> out scale 1/512, * rsqrt(rn), + bias

    prep_all<<<19961, 256, 0, stream>>>(x, Wq, Wk, fc_w, concepts,
                                        x_f8, Wq_bf, Wk_bf, fcw_bf, c_bf, cT_f8, W3T_f8);
    gemm_p2<<<dim3(16, 16), 256, 0, stream>>>(Wq_bf, Wk_bf, P2_bf);
    gemm_batch3<<<320, 256, 0, stream>>>(c_bf, fcw_bf, P2_bf, sim, W3T_f8, W2T_f8);
    // fused scores + sparsemax + rn (32 rows/block, 2 blocks/CU)
    scores_sm_rn<<<B / 32, 256, 0, stream>>>(x_f8, W2T_f8, cT_f8, attn, attn_f8, rn);
    // out = (attn @ W3) * rsqrt(rn) + fc_b   [proven path]
    gemm_f8<float, true, false, true, true><<<dim3((N + 127) / 128, B / 128), 256, 0, stream>>>(
        attn_f8, W3T_f8, fc_b, rn, out, B, N, C, N, 1.0f / 512.0f);
}

// Round 8
// 280.214 us; speedup vs baseline: 1.0236x; 1.0236x over previous
//
#include <hip/hip_runtime.h>
#include <hip/hip_bf16.h>
#include <stdint.h>

typedef __attribute__((ext_vector_type(8))) short short8;
typedef __attribute__((ext_vector_type(4))) float floatx4;
typedef __attribute__((ext_vector_type(8))) int int8v;
typedef __attribute__((ext_vector_type(4))) int int4v;

__device__ __forceinline__ ushort f2b(float f) {
    union { float f; uint32_t u; } v; v.f = f;
    uint32_t r = (v.u + 0x7fffu + ((v.u >> 16) & 1u)) >> 16;
    return (ushort)r;
}
__device__ __forceinline__ float b2f(ushort b) {
    union { uint32_t u; float f; } v; v.u = ((uint32_t)b) << 16;
    return v.f;
}
__device__ __forceinline__ uint8_t f2fp8(float f) {
    return (uint8_t)(__builtin_amdgcn_cvt_pk_fp8_f32(f, f, 0, false) & 0xff);
}

__device__ __forceinline__ void gl_lds16(const void* g, void* l) {
    __builtin_amdgcn_global_load_lds(
        (const __attribute__((address_space(1))) void*)g,
        (__attribute__((address_space(3))) void*)l, 16, 0, 0);
}

// ================= prep mega-kernel: all elementwise/transpose prep in ONE launch ====
__global__ __launch_bounds__(256) void prep_all(
    const float* __restrict__ x, const float* __restrict__ Wq,
    const float* __restrict__ Wk, const float* __restrict__ fcw,
    const float* __restrict__ concepts,
    uint8_t* __restrict__ x_f8, ushort* __restrict__ Wq_bf,
    ushort* __restrict__ Wk_bf, ushort* __restrict__ fcw_bf,
    ushort* __restrict__ c_bf, uint8_t* __restrict__ cT_f8,
    uint8_t* __restrict__ W3T_f8)
{
    __shared__ float smem_f[8];
    __shared__ float partial[32][8];
    __shared__ float invn[32];
    __shared__ uint8_t tile8[32 * 1044];

    int b = blockIdx.x;
    const int tid = threadIdx.x;

    if (b < 16384) {                       // x -> fp8
        int i = b * 256 + tid;
        float4 v = ((const float4*)x)[i];
        int p = __builtin_amdgcn_cvt_pk_fp8_f32(v.x, v.y, 0, false);
        p = __builtin_amdgcn_cvt_pk_fp8_f32(v.z, v.w, p, true);
        ((uint32_t*)x_f8)[i] = p;
        return;
    }
    b -= 16384;
    if (b < 1024) {                        // Wq -> bf16
        int i = b * 256 + tid;
        float4 v = ((const float4*)Wq)[i];
        ushort4 o; o.x = f2b(v.x); o.y = f2b(v.y); o.z = f2b(v.z); o.w = f2b(v.w);
        ((ushort4*)Wq_bf)[i] = o;
        return;
    }
    b -= 1024;
    if (b < 1024) {                        // Wk -> bf16
        int i = b * 256 + tid;
        float4 v = ((const float4*)Wk)[i];
        ushort4 o; o.x = f2b(v.x); o.y = f2b(v.y); o.z = f2b(v.z); o.w = f2b(v.w);
        ((ushort4*)Wk_bf)[i] = o;
        return;
    }
    b -= 1024;
    if (b < 1000) {                        // fc_w -> bf16
        int i = b * 256 + tid;
        float4 v = ((const float4*)fcw)[i];
        ushort4 o; o.x = f2b(v.x); o.y = f2b(v.y); o.z = f2b(v.z); o.w = f2b(v.w);
        ((ushort4*)fcw_bf)[i] = o;
        return;
    }
    b -= 1000;
    if (b < 512) {                         // concept row L2-normalize -> bf16
        const float* xr = concepts + (size_t)b * 1024;
        float vv[4]; float s = 0.0f;
        #pragma unroll
        for (int j = 0; j < 4; j++) { vv[j] = xr[tid + 256 * j]; s += vv[j] * vv[j]; }
        #pragma unroll
        for (int off = 32; off; off >>= 1) s += __shfl_down(s, off, 64);
        if ((tid & 63) == 0) smem_f[tid >> 6] = s;
        __syncthreads();
        float inv = rsqrtf(smem_f[0] + smem_f[1] + smem_f[2] + smem_f[3]);
        ushort* o = c_bf + (size_t)b * 1024;
        #pragma unroll
        for (int j = 0; j < 4; j++) o[tid + 256 * j] = f2b(vv[j] * inv);
        return;
    }
    b -= 512;
    if (b < 16) {                          // cT_f8: rows r0..r0+31, all 1024 cols
        const int r0 = b * 32;
        {
            int row = tid >> 3, sub = tid & 7;
            const float* rp = concepts + (size_t)(r0 + row) * 1024 + sub * 128;
            float s = 0.0f;
            #pragma unroll
            for (int j = 0; j < 32; j++) {
                float4 v = ((const float4*)rp)[j];
                s += v.x * v.x + v.y * v.y + v.z * v.z + v.w * v.w;
            }
            partial[row][sub] = s;
        }
        __syncthreads();
        if (tid < 32) {
            float t = 0.0f;
            #pragma unroll
            for (int j = 0; j < 8; j++) t += partial[tid][j];
            invn[tid] = rsqrtf(t);
        }
        __syncthreads();
        for (int idx = tid; idx < 32 * 256; idx += 256) {
            int row = idx >> 8, d4 = idx & 255;
            float4 v = ((const float4*)(concepts + (size_t)(r0 + row) * 1024))[d4];
            float sc = invn[row] * 16.0f;
            int p = __builtin_amdgcn_cvt_pk_fp8_f32(v.x * sc, v.y * sc, 0, false);
            p = __builtin_amdgcn_cvt_pk_fp8_f32(v.z * sc, v.w * sc, p, true);
            *(uint32_t*)&tile8[row * 1044 + d4 * 4] = p;
        }
        __syncthreads();
        for (int idx = tid; idx < 32 * 1024; idx += 256) {
            int d = idx >> 5, row = idx & 31;
            cT_f8[(size_t)d * 512 + r0 + row] = tile8[row * 1044 + d];
        }
        return;
    }
    {                                      // zero W3T rows 1000..1023
        uint32_t* p = (uint32_t*)(W3T_f8 + 1000 * 512);
        #pragma unroll
        for (int k = 0; k < 12; k++) p[tid + 256 * k] = 0u;
    }
}

// =============== MX-fp8 MFMA GEMM: C = scale*(A @ B^T) [+bias][*rsqrt(rn)] ==========
template<typename OutT, bool NGUARD, bool SUMSQ, bool ROWSCALE, bool STORE>
__global__ __launch_bounds__(256, 3) void gemm_f8(
    const uint8_t* __restrict__ A, const uint8_t* __restrict__ B,
    const float* __restrict__ bias, float* __restrict__ rn, OutT* __restrict__ C,
    int M, int N, int K, int Nld, float scale)
{
    __shared__ alignas(16) uint8_t As[128 * 128];
    __shared__ alignas(16) uint8_t Bs[128 * 128];
    const int id = threadIdx.x;
    const int wave = id >> 6, lane = id & 63;

    int bxi = blockIdx.x, byi = blockIdx.y;
    if ((gridDim.y & 7) == 0) {
        int i = byi * gridDim.x + bxi;
        int xcd = i & 7;
        int j = i >> 3;
        bxi = j % gridDim.x;
        byi = xcd + 8 * (j / gridDim.x);
    }
    const int row0 = byi * 128, col0 = bxi * 128;
    const int wm = (wave >> 1) * 64, wn = (wave & 1) * 64;

    const int fr = id >> 3;
    const int fss = (id & 7) ^ (fr & 7);
    const uint8_t* Agp[4];
    const uint8_t* Bgp[4];
    #pragma unroll
    for (int t = 0; t < 4; t++) {
        int ar = row0 + fr + 32 * t;
        int br = col0 + fr + 32 * t;
        if (NGUARD) br = min(br, N - 1);
        Agp[t] = A + (size_t)ar * K + fss * 16;
        Bgp[t] = B + (size_t)br * K + fss * 16;
    }

    floatx4 acc[4][4] = {};
    const int mrow = lane & 15;
    const int g2 = (lane >> 4) * 2;

    for (int k0 = 0; k0 < K; k0 += 128) {
        #pragma unroll
        for (int t = 0; t < 4; t++) {
            gl_lds16(Agp[t] + k0, &As[id * 16 + 4096 * t]);
            gl_lds16(Bgp[t] + k0, &Bs[id * 16 + 4096 * t]);
        }
        __syncthreads();
        int8v a[4], b[4];
        #pragma unroll
        for (int i = 0; i < 4; i++) {
            int r = wm + i * 16 + mrow, rs = r & 7;
            int4v lo = *(const int4v*)&As[r * 128 + ((g2    ) ^ rs) * 16];
            int4v hi = *(const int4v*)&As[r * 128 + ((g2 + 1) ^ rs) * 16];
            a[i] = __builtin_shufflevector(lo, hi, 0, 1, 2, 3, 4, 5, 6, 7);
        }
        #pragma unroll
        for (int j = 0; j < 4; j++) {
            int r = wn + j * 16 + mrow, rs = r & 7;
            int4v lo = *(const int4v*)&Bs[r * 128 + ((g2    ) ^ rs) * 16];
            int4v hi = *(const int4v*)&Bs[r * 128 + ((g2 + 1) ^ rs) * 16];
            b[j] = __builtin_shufflevector(lo, hi, 0, 1, 2, 3, 4, 5, 6, 7);
        }
        #pragma unroll
        for (int i = 0; i < 4; i++)
            #pragma unroll
            for (int j = 0; j < 4; j++)
                acc[i][j] = __builtin_amdgcn_mfma_scale_f32_16x16x128_f8f6f4(
                    a[i], b[j], acc[i][j], 0, 0, 0, 0x7f7f7f7f, 0, 0x7f7f7f7f);
        __syncthreads();
    }

    const int ccol0 = col0 + wn + (lane & 15);
    const int crow0 = row0 + wm + (lane >> 4) * 4;
    float bv[4];
    #pragma unroll
    for (int j = 0; j < 4; j++) {
        int col = ccol0 + j * 16;
        bv[j] = (bias && (!NGUARD || col < N)) ? bias[col] : 0.0f;
    }
    #pragma unroll
    for (int i = 0; i < 4; i++) {
        #pragma unroll
        for (int r = 0; r < 4; r++) {
            const int row = crow0 + i * 16 + r;
            float inv = 1.0f;
            if constexpr (ROWSCALE) inv = rsqrtf(rn[row]);
            float ss = 0.0f;
            #pragma unroll
            for (int j = 0; j < 4; j++) {
                int col = ccol0 + j * 16;
                float v = acc[i][j][r] * scale * inv + bv[j];
                if constexpr (SUMSQ) ss += v * v;
                if constexpr (STORE) {
                    if (!NGUARD || col < N) {
                        if constexpr (sizeof(OutT) == 1)      C[(size_t)row * Nld + col] = (OutT)f2fp8(v);
                        else if constexpr (sizeof(OutT) == 2) C[(size_t)row * Nld + col] = (OutT)f2b(v);
                        else                                   C[(size_t)row * Nld + col] = v;
                    }
                }
            }
            if constexpr (SUMSQ) {
                #pragma unroll
                for (int m = 1; m < 16; m <<= 1) ss += __shfl_xor(ss, m, 64);
                if ((lane & 15) == 0) atomicAdd(&rn[row], ss);
            }
        }
    }
}

// =============== shared 64x64 bf16 GEMM body ==========
__device__ __forceinline__ void gemm64_body(
    uint8_t* As, uint8_t* Bs,
    const ushort* __restrict__ A, const ushort* __restrict__ B, void* Cout, int outmode,
    int M, int N, int K, int Nld, float scale, int bx, int by, bool mguard)
{
    const int id = threadIdx.x;
    const int wave = id >> 6, lane = id & 63;
    const int row0 = by * 64, col0 = bx * 64;
    const int wm = (wave >> 1) * 32, wn = (wave & 1) * 32;

    const int fr = id >> 4;
    const int sch = (id & 15) ^ (fr & 7);
    const uint8_t* Ab = (const uint8_t*)A;
    const uint8_t* Bb = (const uint8_t*)B;
    const uint8_t* Agp[4];
    const uint8_t* Bgp[4];
    #pragma unroll
    for (int t = 0; t < 4; t++) {
        int ar = row0 + fr + 16 * t;
        if (mguard) ar = min(ar, M - 1);
        int br = col0 + fr + 16 * t;
        Agp[t] = Ab + (size_t)ar * (K * 2) + sch * 16;
        Bgp[t] = Bb + (size_t)br * (K * 2) + sch * 16;
    }

    floatx4 acc[2][2] = {};
    const int mrow = lane & 15, g = lane >> 4;

    for (int k0 = 0; k0 < K; k0 += 128) {
        #pragma unroll
        for (int t = 0; t < 4; t++) {
            gl_lds16(Agp[t] + (size_t)k0 * 2, &As[id * 16 + 4096 * t]);
            gl_lds16(Bgp[t] + (size_t)k0 * 2, &Bs[id * 16 + 4096 * t]);
        }
        __syncthreads();
        #pragma unroll
        for (int ks = 0; ks < 4; ks++) {
            short8 a[2], b[2];
            #pragma unroll
            for (int i = 0; i < 2; i++) {
                int r = wm + i * 16 + mrow;
                a[i] = *(const short8*)&As[r * 256 + ((ks * 4 + g) ^ (r & 7)) * 16];
            }
            #pragma unroll
            for (int j = 0; j < 2; j++) {
                int r = wn + j * 16 + mrow;
                b[j] = *(const short8*)&Bs[r * 256 + ((ks * 4 + g) ^ (r & 7)) * 16];
            }
            #pragma unroll
            for (int i = 0; i < 2; i++)
                #pragma unroll
                for (int j = 0; j < 2; j++)
                    acc[i][j] = __builtin_amdgcn_mfma_f32_16x16x32_bf16(a[i], b[j], acc[i][j], 0, 0, 0);
        }
        __syncthreads();
    }

    const int ccol0 = col0 + wn + (lane & 15);
    const int crow0 = row0 + wm + (lane >> 4) * 4;
    #pragma unroll
    for (int i = 0; i < 2; i++) {
        #pragma unroll
        for (int r = 0; r < 4; r++) {
            const int row = crow0 + i * 16 + r;
            if (mguard && row >= M) continue;
            #pragma unroll
            for (int j = 0; j < 2; j++) {
                int col = ccol0 + j * 16;
                float v = acc[i][j][r] * scale;
                if (outmode == 0)      ((float*)Cout)[(size_t)row * Nld + col] = v;
                else if (outmode == 1) ((uint8_t*)Cout)[(size_t)row * Nld + col] = f2fp8(v);
                else                   ((ushort*)Cout)[(size_t)row * Nld + col] = f2b(v);
            }
        }
    }
}

// P2 = Wq @ Wk^T   [1024,1024] bf16
__global__ __launch_bounds__(256) void gemm_p2(const ushort* __restrict__ Wq_bf,
                                               const ushort* __restrict__ Wk_bf,
                                               ushort* __restrict__ P2) {
    __shared__ alignas(16) uint8_t As[64 * 256];
    __shared__ alignas(16) uint8_t Bs[64 * 256];
    gemm64_body(As, Bs, Wq_bf, Wk_bf, P2, 2, 1024, 1024, 1024, 1024, 1.0f,
                blockIdx.x, blockIdx.y, false);
}

// batched: sim = c@c^T (f32) | W3T = fcw@c^T (fp8*16) | W2T = c@P2^T (fp8*16)
__global__ __launch_bounds__(256) void gemm_batch3(
    const ushort* __restrict__ c_bf, const ushort* __restrict__ fcw_bf,
    const ushort* __restrict__ P2,
    float* __restrict__ sim, uint8_t* __restrict__ W3T, uint8_t* __restrict__ W2T)
{
    __shared__ alignas(16) uint8_t As[64 * 256];
    __shared__ alignas(16) uint8_t Bs[64 * 256];
    int b = blockIdx.x;
    if (b < 64) {
        gemm64_body(As, Bs, c_bf, c_bf, sim, 0, 512, 512, 1024, 512, 1.0f, b & 7, b >> 3, false);
    } else if (b < 192) {
        b -= 64;
        gemm64_body(As, Bs, fcw_bf, c_bf, W3T, 1, 1000, 512, 1024, 512, 16.0f, b & 7, b >> 3, true);
    } else {
        b -= 192;
        gemm64_body(As, Bs, c_bf, P2, W2T, 1, 512, 1024, 1024, 1024, 16.0f, b & 15, b >> 4, false);
    }
}

// ===== fused scores + sparsemax + rn: 32 rows/block, 512 blocks, 2 blocks/CU =====
// Phase 1: scores GEMM with ALL fragments direct from L2 (no LDS staging, no barriers,
//          no global_load_lds). Wave owns 32 rows x 128 cols (acc[2][8]).
// Phase 2: f32 scores -> LDS sc (chunk-XOR swizzle, R7-proven) -> per-lane full row
//          -> wave-local Newton sparsemax (R7-proven math); tau -> LDS.
// Phase 3: coalesced copier: sc -> attn f32 (16B/lane consecutive) + A8 fp8 (4B/lane
//          consecutive) + at8 LDS overlay (phased so overlay only hits consumed chunks).
// Phase 4: rn = |attn @ c|^2; A-frags from LDS at8, B-frags direct from L2-resident cT
//          (R7-proven), block-local reduce, direct write.
__global__ __launch_bounds__(256, 2) void scores_sm_rn(
    const uint8_t* __restrict__ X, const uint8_t* __restrict__ W2T,
    const uint8_t* __restrict__ cT,
    float* __restrict__ attn, uint8_t* __restrict__ A8, float* __restrict__ rn)
{
    // LDS 66560 B: sc f32[32][512] (chunk-swizzled) [0,65536) ; at8 fp8[32][512] overlays
    // [0,16384) (only after those sc chunks are consumed); tauv [65536,+128); rnred [+128,+640)
    __shared__ alignas(16) uint8_t lds[66560];
    float*   sc    = (float*)lds;
    uint8_t* at8   = lds;
    float*   tauv  = (float*)(lds + 65536);
    float*   rnred = (float*)(lds + 65536 + 128);

    const int id = threadIdx.x;
    const int wave = id >> 6, lane = id & 63;
    const int row0 = blockIdx.x * 32;
    const int mrow = lane & 15;
    const int g = lane >> 4;
    const int g2 = g * 2;

    // ---------------- phase 1: scores GEMM, fragments direct from L2 ----------------
    {
        const uint8_t* Arow[2];
        #pragma unroll
        for (int mt = 0; mt < 2; mt++)
            Arow[mt] = X + (size_t)(row0 + mt * 16 + mrow) * 1024 + g2 * 16;
        const uint8_t* Brow[8];
        #pragma unroll
        for (int j = 0; j < 8; j++)
            Brow[j] = W2T + (size_t)(wave * 128 + j * 16 + mrow) * 1024 + g2 * 16;

        floatx4 acc[2][8] = {};
        for (int k0 = 0; k0 < 1024; k0 += 128) {
            int8v a[2], b[8];
            #pragma unroll
            for (int mt = 0; mt < 2; mt++) {
                int4v lo = *(const int4v*)(Arow[mt] + k0);
                int4v hi = *(const int4v*)(Arow[mt] + k0 + 16);
                a[mt] = __builtin_shufflevector(lo, hi, 0, 1, 2, 3, 4, 5, 6, 7);
            }
            #pragma unroll
            for (int j = 0; j < 8; j++) {
                int4v lo = *(const int4v*)(Brow[j] + k0);
                int4v hi = *(const int4v*)(Brow[j] + k0 + 16);
                b[j] = __builtin_shufflevector(lo, hi, 0, 1, 2, 3, 4, 5, 6, 7);
            }
            #pragma unroll
            for (int mt = 0; mt < 2; mt++)
                #pragma unroll
                for (int j = 0; j < 8; j++)
                    acc[mt][j] = __builtin_amdgcn_mfma_scale_f32_16x16x128_f8f6f4(
                        a[mt], b[j], acc[mt][j], 0, 0, 0, 0x7f7f7f7f, 0, 0x7f7f7f7f);
        }

        // scores (scaled) -> sc with 16B-chunk XOR swizzle (R7-proven word-exact round trip)
        #pragma unroll
        for (int mt = 0; mt < 2; mt++)
            #pragma unroll
            for (int j = 0; j < 8; j++) {
                int col = wave * 128 + j * 16 + mrow;
                int c = col >> 2, w2 = col & 3;
                #pragma unroll
                for (int r = 0; r < 4; r++) {
                    int row = mt * 16 + g * 4 + r;
                    sc[row * 512 + ((c ^ (row & 7)) << 2) + w2] = acc[mt][j][r] * (1.0f / 512.0f);
                }
            }
    }
    __syncthreads();

    // ---------------- phase 2: per-lane full row -> wave-local Newton ----------------
    {
        const int orow = wave * 8 + (lane >> 3);    // owned row 0..31
        const int cc = lane & 7;                    // col block cc*64..+63
        const int ors = orow & 7;
        float4 v4[16];
        #pragma unroll
        for (int k4 = 0; k4 < 16; k4++) {
            int phys = (cc * 16 + k4) ^ ors;
            v4[k4] = *(const float4*)&sc[orow * 512 + phys * 4];
        }
        float mx = v4[0].x;
        #pragma unroll
        for (int k4 = 0; k4 < 16; k4++)
            mx = fmaxf(mx, fmaxf(fmaxf(v4[k4].x, v4[k4].y), fmaxf(v4[k4].z, v4[k4].w)));
        #pragma unroll
        for (int off = 1; off < 8; off <<= 1) mx = fmaxf(mx, __shfl_xor(mx, off, 64));
        // Newton on f(tau)=sum(max(v-tau,0))-1: monotone from below, k>=1 always.
        float tau = mx - 1.0f;
        for (int it = 0; it < 12; it++) {
            float s = 0.0f, k = 0.0f;
            #pragma unroll
            for (int k4 = 0; k4 < 16; k4++) {
                float d;
                d = v4[k4].x - tau; if (d > 0.0f) { s += d; k += 1.0f; }
                d = v4[k4].y - tau; if (d > 0.0f) { s += d; k += 1.0f; }
                d = v4[k4].z - tau; if (d > 0.0f) { s += d; k += 1.0f; }
                d = v4[k4].w - tau; if (d > 0.0f) { s += d; k += 1.0f; }
            }
            #pragma unroll
            for (int off = 1; off < 8; off <<= 1) {
                s += __shfl_xor(s, off, 64);
                k += __shfl_xor(k, off, 64);
            }
            tau += (s - 1.0f) / k;
        }
        if (cc == 0) tauv[orow] = tau;
    }
    __syncthreads();

    // ------- phase 3: coalesced copier sc -> attn (f32) + A8 (fp8) + at8 (LDS) -------
    // 4096 16B-chunks over 16 iters. iters 0-3 cover sc chunks [0,1024) (rows 0-7) whose
    // at8 overlay region [0,16384) is still live sc -> stash fp8, write after barrier.
    {
        uint32_t pst[4];
        #pragma unroll
        for (int i = 0; i < 16; i++) {
            if (i == 4) {
                __syncthreads();            // sc chunks [0,1024) consumed by all waves
                #pragma unroll
                for (int s = 0; s < 4; s++) {
                    int chunk = s * 256 + id;
                    int row = chunk >> 7, cc = chunk & 127;
                    *(uint32_t*)&at8[row * 512 + (((cc >> 2) ^ (row & 7)) << 4) + (cc & 3) * 4] = pst[s];
                }
            }
            int chunk = i * 256 + id;
            int row = chunk >> 7, cc = chunk & 127;
            float4 v = *(const float4*)&sc[row * 512 + ((cc ^ (row & 7)) << 2)];
            float tau = tauv[row];
            float4 o;
            o.x = fmaxf(v.x - tau, 0.0f);
            o.y = fmaxf(v.y - tau, 0.0f);
            o.z = fmaxf(v.z - tau, 0.0f);
            o.w = fmaxf(v.w - tau, 0.0f);
            *(float4*)(attn + (size_t)(row0 + row) * 512 + cc * 4) = o;
            int p = __builtin_amdgcn_cvt_pk_fp8_f32(o.x * 32.0f, o.y * 32.0f, 0, false);
            p = __builtin_amdgcn_cvt_pk_fp8_f32(o.z * 32.0f, o.w * 32.0f, p, true);
            *(uint32_t*)(A8 + (size_t)(row0 + row) * 512 + cc * 4) = (uint32_t)p;
            if (i < 4) pst[i] = (uint32_t)p;    // overlay region still live -> stash
            else *(uint32_t*)&at8[row * 512 + (((cc >> 2) ^ (row & 7)) << 4) + (cc & 3) * 4] = (uint32_t)p;
        }
    }
    __syncthreads();

    // ---------------- cached A-fragments (attn 32 rows, K=512) from at8 ----------------
    int8v a_all[2][4];
    #pragma unroll
    for (int mt = 0; mt < 2; mt++) {
        const int ar = mt * 16 + mrow;
        const int rs = ar & 7;
        #pragma unroll
        for (int ks = 0; ks < 4; ks++) {
            int4v lo = *(const int4v*)&at8[ar * 512 + (((ks * 8 + g2    ) ^ rs) << 4)];
            int4v hi = *(const int4v*)&at8[ar * 512 + (((ks * 8 + g2 + 1) ^ rs) << 4)];
            a_all[mt][ks] = __builtin_shufflevector(lo, hi, 0, 1, 2, 3, 4, 5, 6, 7);
        }
    }

    // ---------------- phase 4: rn, B-frags direct from L2-resident cT ----------------
    float ss[8] = {};
    #pragma unroll 2
    for (int seg = 0; seg < 16; seg++) {
        const int col = seg * 64 + wave * 16 + mrow;         // cT row 0..1023
        const uint8_t* bp = cT + (size_t)col * 512 + g * 32;
        floatx4 acc_t[2] = {};
        #pragma unroll
        for (int ks = 0; ks < 4; ks++) {
            int4v lo = *(const int4v*)(bp + ks * 128);
            int4v hi = *(const int4v*)(bp + ks * 128 + 16);
            int8v b = __builtin_shufflevector(lo, hi, 0, 1, 2, 3, 4, 5, 6, 7);
            acc_t[0] = __builtin_amdgcn_mfma_scale_f32_16x16x128_f8f6f4(
                a_all[0][ks], b, acc_t[0], 0, 0, 0, 0x7f7f7f7f, 0, 0x7f7f7f7f);
            acc_t[1] = __builtin_amdgcn_mfma_scale_f32_16x16x128_f8f6f4(
                a_all[1][ks], b, acc_t[1], 0, 0, 0, 0x7f7f7f7f, 0, 0x7f7f7f7f);
        }
        #pragma unroll
        for (int mt = 0; mt < 2; mt++)
            #pragma unroll
            for (int r = 0; r < 4; r++) {
                float v = acc_t[mt][r] * (1.0f / 512.0f);
                ss[mt * 4 + r] += v * v;
            }
    }

    #pragma unroll
    for (int i = 0; i < 8; i++) {
        #pragma unroll
        for (int off = 1; off < 16; off <<= 1) ss[i] += __shfl_xor(ss[i], off, 64);
    }
    if (mrow == 0) {
        #pragma unroll
        for (int mt = 0; mt < 2; mt++)
            #pragma unroll
            for (int r = 0; r < 4; r++)
                rnred[wave * 32 + mt * 16 + g * 4 + r] = ss[mt * 4 + r];
    }
    __syncthreads();
    if (id < 32)
        rn[row0 + id] = rnred[id] + rnred[32 + id] + rnred[64 + id] + rnred[96 + id];
}

extern "C" void kernel_launch(void* const* d_in, const int* in_sizes, int n_in,
                              void* d_out, int out_size, void* d_ws, size_t ws_size,
                              hipStream_t stream) {
    const float* x        = (const float*)d_in[0];   // [16384,1024]
    const float* concepts = (const float*)d_in[1];   // [512,1024]
    const float* Wq       = (const float*)d_in[2];   // [1024,1024]
    const float* Wk       = (const float*)d_in[3];   // [1024,1024]
    const float* fc_w     = (const float*)d_in[4];   // [1000,1024]
    const float* fc_b     = (const float*)d_in[5];   // [1000]

    const int B = 16384, D = 1024, C = 512, N = 1000;

    float* out  = (float*)d_out;                       // [B,N]
    float* attn = out + (size_t)B * N;                 // [B,C]
    float* sim  = attn + (size_t)B * C;                // [C,C]

    // ---- ws layout (~34.6 MiB) ----
    uint8_t* w = (uint8_t*)d_ws;
    uint8_t* x_f8    = w;                                        // [B,D]     16 MiB
    uint8_t* attn_f8 = w + (16ull << 20);                        // [B,C]      8 MiB
    ushort*  Wq_bf   = (ushort*)(w + (24ull << 20));             // [D,D]      2 MiB
    ushort*  Wk_bf   = (ushort*)(w + (26ull << 20));             // [D,D]      2 MiB
    ushort*  fcw_bf  = (ushort*)(w + (28ull << 20));             // [N,D]      2 MiB
    ushort*  c_bf    = (ushort*)(w + (30ull << 20));             // [C,D]      1 MiB
    ushort*  P2_bf   = (ushort*)(w + (31ull << 20));             // [D,D]      2 MiB
    uint8_t* cT_f8   = w + (33ull << 20);                        // [D,C]    0.5 MiB
    uint8_t* W2T_f8  = w + (33ull << 20) + (512ull << 10);       // [C,D]    0.5 MiB
    uint8_t* W3T_f8  = w + (34ull << 20);                        // [1024,C] 0.5 MiB (tail rows zeroed)
    float*   rn      = (float*)(w + (34ull << 20) + (512ull << 10)); // [B] 64 KiB

    // Reassociation: scores = x @ W2T^T where W2T = c @ (Wq Wk^T)^T  (P2 = Wq @ Wk^T)
    //                out    = (attn @ W3T^T) * rsqrt(|attn@c|^2) + b (W3T = fcw @ c^T)
    // scales: x*1, W2T*16 -> scores scale (1/32)/16 = 1/512 (f32)
    //         attn*32, cT*16 -> rn = |acc/512|^2 (in-kernel, direct write)
    //         attn*32, W3T*16 -> out scale 1/512, * rsqrt(rn), + bias

    prep_all<<<19961, 256, 0, stream>>>(x, Wq, Wk, fc_w, concepts,
                                        x_f8, Wq_bf, Wk_bf, fcw_bf, c_bf, cT_f8, W3T_f8);
    gemm_p2<<<dim3(16, 16), 256, 0, stream>>>(Wq_bf, Wk_bf, P2_bf);
    gemm_batch3<<<320, 256, 0, stream>>>(c_bf, fcw_bf, P2_bf, sim, W3T_f8, W2T_f8);
    // fused scores + sparsemax + rn (direct-L2 fragments, no staging)
    scores_sm_rn<<<B / 32, 256, 0, stream>>>(x_f8, W2T_f8, cT_f8, attn, attn_f8, rn);
    // out = (attn @ W3) * rsqrt(rn) + fc_b   [proven path]
    gemm_f8<float, true, false, true, true><<<dim3((N + 127) / 128, B / 128), 256, 0, stream>>>(
        attn_f8, W3T_f8, fc_b, rn, out, B, N, C, N, 1.0f / 512.0f);
}